// Round 3
// baseline (139.519 us; speedup 1.0000x reference)
//
#include <hip/hip_runtime.h>
#include <cstdint>
#include <cstddef>

#define BB 4
#define NN 16384
#define SS 4096
#define CC 64
#define NSAMP 64
// radius*radius: python double 0.04000000000000000083 -> f32 compare -> 0.04f
#define R2 0.04f

#define TRANS_BLOCKS (BB * (NN / 64))   // 1024
#define BQ_BLOCKS    (BB * SS / 4)      // 4096 blocks x 4 waves = 16384 queries

typedef float  f32x4 __attribute__((ext_vector_type(4)));

// ---------------------------------------------------------------------------
// Kernel 1 (merged): blocks [0,1024) transpose features (B,C,N)->(B,N,C);
// blocks [1024,5120) run ball query, one query per wave (4 waves/block).
// Ball query result (after first-index fill) written to idxbuf[q][64].
// ---------------------------------------------------------------------------
__global__ __launch_bounds__(256) void prep_kernel(const float* __restrict__ xyz,
                                                   const float* __restrict__ nxyz,
                                                   const float* __restrict__ feat,
                                                   float* __restrict__ featT,
                                                   int* __restrict__ idxbuf) {
    __shared__ float tile[64][65];   // transpose tile; ball-query aliases 1KB of it
    int t = threadIdx.x;

    if (blockIdx.x < TRANS_BLOCKS) {
        // ---- feature transpose ----
        int blk = blockIdx.x;
        int b   = blk / (NN / 64);
        int n0  = (blk % (NN / 64)) * 64;
        int nl  = t & 63;
        int cq  = t >> 6;
#pragma unroll
        for (int p = 0; p < 16; ++p) {
            int c = cq + p * 4;
            tile[c][nl] = feat[((size_t)b * CC + c) * NN + n0 + nl];   // coalesced
        }
        __syncthreads();
#pragma unroll
        for (int p = 0; p < 16; ++p) {
            int nl2 = cq + p * 4;
            featT[((size_t)b * NN + n0 + nl2) * CC + nl] = tile[nl][nl2]; // coalesced
        }
        return;
    }

    // ---- ball query: 4 independent waves, one query each ----
    int wid  = t >> 6;
    int lane = t & 63;
    int q    = (blockIdx.x - TRANS_BLOCKS) * 4 + wid;
    int b    = q >> 12;          // q / SS
    int s    = q & (SS - 1);

    volatile int* sidx = (volatile int*)tile + wid * NSAMP;  // per-wave 64 ints

    const float* xb = xyz + (size_t)b * NN * 3;
    float qx = nxyz[((size_t)b * SS + s) * 3 + 0];
    float qy = nxyz[((size_t)b * SS + s) * 3 + 1];
    float qz = nxyz[((size_t)b * SS + s) * 3 + 2];
    // q2 = (qx*qx + qy*qy) + qz*qz  -- numpy f32 sequential, no FMA contraction
    float q2 = __fadd_rn(__fadd_rn(__fmul_rn(qx, qx), __fmul_rn(qy, qy)),
                         __fmul_rn(qz, qz));

    int cnt = 0;
    float px = xb[(size_t)lane * 3 + 0];
    float py = xb[(size_t)lane * 3 + 1];
    float pz = xb[(size_t)lane * 3 + 2];
    for (int base = 0; base < NN; base += 64) {
        float cx = px, cy = py, cz = pz;
        int nb = base + 64;
        if (nb < NN) {   // uniform; prefetch next chunk
            px = xb[(size_t)(nb + lane) * 3 + 0];
            py = xb[(size_t)(nb + lane) * 3 + 1];
            pz = xb[(size_t)(nb + lane) * 3 + 2];
        }
        float p2 = __fadd_rn(__fadd_rn(__fmul_rn(cx, cx), __fmul_rn(cy, cy)),
                             __fmul_rn(cz, cz));
        float qp = __fadd_rn(__fadd_rn(__fmul_rn(qx, cx), __fmul_rn(qy, cy)),
                             __fmul_rn(qz, cz));
        float d2 = __fsub_rn(__fadd_rn(q2, p2), __fadd_rn(qp, qp));
        bool in = d2 < R2;
        unsigned long long m = __ballot(in);
        if (in) {
            int pos = cnt + __popcll(m & ((1ull << lane) - 1ull));
            if (pos < NSAMP) sidx[pos] = base + lane;
        }
        cnt += __popcll(m);
        if (cnt >= NSAMP) break;   // uniform
    }
    // wave-synchronous LDS: drain ds ops, forbid reordering (no block barrier)
    asm volatile("s_waitcnt lgkmcnt(0)" ::: "memory");
    int total  = cnt < NSAMP ? cnt : NSAMP;
    int myidx  = (total == 0) ? 0 : ((lane < total) ? sidx[lane] : sidx[0]);
    idxbuf[(size_t)q * NSAMP + lane] = myidx;   // coalesced
}

// ---------------------------------------------------------------------------
// Kernel 2: grouping. One query per 256-thread block, pure streaming.
// Coalesced 256B featT row gathers -> 64x65 LDS tile -> non-temporal float4
// coalesced stores. 16.9KB LDS -> 8 blocks/CU -> 32 waves/CU (100%).
// ---------------------------------------------------------------------------
__global__ __launch_bounds__(256) void group_kernel(const float* __restrict__ xyz,
                                                    const float* __restrict__ nxyz,
                                                    const float* __restrict__ featT,
                                                    const int* __restrict__ idxbuf,
                                                    float* __restrict__ out) {
    __shared__ float tile[64][65];
    __shared__ int   sidx[64];

    int wg = blockIdx.x;
    // XCD swizzle: 16384 % 8 == 0 -> bijective; each XCD works one half-batch
    // so its featT slice (~4MB) matches one XCD L2.
    int q  = (wg & 7) * (BB * SS / 8) + (wg >> 3);
    int b  = q >> 12;
    int s  = q & (SS - 1);
    int t  = threadIdx.x;

    if (t < 64) sidx[t] = idxbuf[(size_t)q * NSAMP + t];
    __syncthreads();

    const float* ftb = featT + (size_t)b * NN * CC;
    int rsub = t >> 4;        // 0..15
    int cf4  = t & 15;        // 0..15 (float4 column)
#pragma unroll
    for (int j = 0; j < 4; ++j) {
        int row = j * 16 + rsub;
        int pr  = sidx[row];
        const f32x4 v = *(const f32x4*)(ftb + (size_t)pr * CC + cf4 * 4);
        tile[row][cf4 * 4 + 0] = v.x;
        tile[row][cf4 * 4 + 1] = v.y;
        tile[row][cf4 * 4 + 2] = v.z;
        tile[row][cf4 * 4 + 3] = v.w;
    }

    size_t obase = ((size_t)b * 67) * SS * 64 + (size_t)s * 64;
    size_t chs   = (size_t)SS * 64;

    // grouped_xyz channels 0..2 (wave 0 only; broadcast query reads)
    if (t < 64) {
        int id = sidx[t];
        float qx = nxyz[((size_t)b * SS + s) * 3 + 0];
        float qy = nxyz[((size_t)b * SS + s) * 3 + 1];
        float qz = nxyz[((size_t)b * SS + s) * 3 + 2];
        const float* xb = xyz + (size_t)b * NN * 3;
        float gx = __fsub_rn(xb[(size_t)id * 3 + 0], qx);
        float gy = __fsub_rn(xb[(size_t)id * 3 + 1], qy);
        float gz = __fsub_rn(xb[(size_t)id * 3 + 2], qz);
        __builtin_nontemporal_store(gx, out + obase + 0 * chs + t);
        __builtin_nontemporal_store(gy, out + obase + 1 * chs + t);
        __builtin_nontemporal_store(gz, out + obase + 2 * chs + t);
    }
    __syncthreads();

    // grouped features channels 3..66: transposed reads, coalesced nt stores
    int k4 = t & 15;
#pragma unroll
    for (int j = 0; j < 4; ++j) {
        int c = j * 16 + (t >> 4);
        f32x4 o;
        o.x = tile[k4 * 4 + 0][c];
        o.y = tile[k4 * 4 + 1][c];
        o.z = tile[k4 * 4 + 2][c];
        o.w = tile[k4 * 4 + 3][c];
        __builtin_nontemporal_store(o, (f32x4*)(out + obase + (size_t)(3 + c) * chs + k4 * 4));
    }
}

// ---------------------------------------------------------------------------
// Fallback (ws too small): fused one-wave-per-query, direct (C,N) gather.
// ---------------------------------------------------------------------------
__global__ __launch_bounds__(64) void qg_fallback(const float* __restrict__ xyz,
                                                  const float* __restrict__ nxyz,
                                                  const float* __restrict__ feat,
                                                  float* __restrict__ out) {
    __shared__ int sidx[NSAMP];
    int q = blockIdx.x;
    int b = q >> 12, s = q & (SS - 1);
    int lane = threadIdx.x;
    const float* xb = xyz + (size_t)b * NN * 3;
    float qx = nxyz[((size_t)b * SS + s) * 3 + 0];
    float qy = nxyz[((size_t)b * SS + s) * 3 + 1];
    float qz = nxyz[((size_t)b * SS + s) * 3 + 2];
    float q2 = __fadd_rn(__fadd_rn(__fmul_rn(qx, qx), __fmul_rn(qy, qy)),
                         __fmul_rn(qz, qz));
    int cnt = 0;
    for (int base = 0; base < NN; base += 64) {
        float cx = xb[(size_t)(base + lane) * 3 + 0];
        float cy = xb[(size_t)(base + lane) * 3 + 1];
        float cz = xb[(size_t)(base + lane) * 3 + 2];
        float p2 = __fadd_rn(__fadd_rn(__fmul_rn(cx, cx), __fmul_rn(cy, cy)),
                             __fmul_rn(cz, cz));
        float qp = __fadd_rn(__fadd_rn(__fmul_rn(qx, cx), __fmul_rn(qy, cy)),
                             __fmul_rn(qz, cz));
        float d2 = __fsub_rn(__fadd_rn(q2, p2), __fadd_rn(qp, qp));
        bool in = d2 < R2;
        unsigned long long m = __ballot(in);
        if (in) {
            int pos = cnt + __popcll(m & ((1ull << lane) - 1ull));
            if (pos < NSAMP) sidx[pos] = base + lane;
        }
        cnt += __popcll(m);
        if (cnt >= NSAMP) break;
    }
    __syncthreads();
    int total = cnt < NSAMP ? cnt : NSAMP;
    int myidx = (total == 0) ? 0 : ((lane < total) ? sidx[lane] : sidx[0]);
    size_t obase = ((size_t)b * 67) * SS * 64 + (size_t)s * 64;
    size_t chs   = (size_t)SS * 64;
    out[obase + 0 * chs + lane] = __fsub_rn(xb[(size_t)myidx * 3 + 0], qx);
    out[obase + 1 * chs + lane] = __fsub_rn(xb[(size_t)myidx * 3 + 1], qy);
    out[obase + 2 * chs + lane] = __fsub_rn(xb[(size_t)myidx * 3 + 2], qz);
    const float* fb = feat + (size_t)b * CC * NN;
#pragma unroll 4
    for (int c = 0; c < CC; ++c)
        out[obase + (size_t)(3 + c) * chs + lane] = fb[(size_t)c * NN + myidx];
}

// ---------------------------------------------------------------------------
extern "C" void kernel_launch(void* const* d_in, const int* in_sizes, int n_in,
                              void* d_out, int out_size, void* d_ws, size_t ws_size,
                              hipStream_t stream) {
    const float* xyz  = (const float*)d_in[0];   // (B,N,3)
    const float* nxyz = (const float*)d_in[1];   // (B,S,3)
    const float* feat = (const float*)d_in[2];   // (B,C,N)
    float* out = (float*)d_out;                  // (B,67,S,64)

    size_t needT = (size_t)BB * NN * CC * sizeof(float);          // 16 MB
    size_t needI = (size_t)BB * SS * NSAMP * sizeof(int);         //  4 MB
    if (ws_size >= needT + needI) {
        float* featT = (float*)d_ws;
        int*   idxb  = (int*)((char*)d_ws + needT);
        prep_kernel<<<TRANS_BLOCKS + BQ_BLOCKS, 256, 0, stream>>>(xyz, nxyz, feat,
                                                                  featT, idxb);
        group_kernel<<<BB * SS, 256, 0, stream>>>(xyz, nxyz, featT, idxb, out);
    } else {
        qg_fallback<<<BB * SS, 64, 0, stream>>>(xyz, nxyz, feat, out);
    }
}

// Round 4
// 89.572 us; speedup vs baseline: 1.5576x; 1.5576x over previous
//
#include <hip/hip_runtime.h>
#include <cstdint>
#include <cstddef>

#define BB 4
#define NN 16384
#define SS 4096
#define CC 64
#define NSAMP 64
// radius*radius: python double 0.04000000000000000083 -> f32 compare -> 0.04f
#define R2 0.04f

typedef float f32x4 __attribute__((ext_vector_type(4)));

// ---------------------------------------------------------------------------
// Kernel 1: transpose features (B,C,N) -> featT (B,N,C). 32 MB traffic ~ 6us.
// ---------------------------------------------------------------------------
__global__ __launch_bounds__(256) void transpose_feat(const float* __restrict__ f,
                                                      float* __restrict__ ft) {
    __shared__ float tile[64][65];
    int blk = blockIdx.x;
    int b   = blk / (NN / 64);
    int n0  = (blk % (NN / 64)) * 64;
    int t   = threadIdx.x;
    int nl  = t & 63;
    int cq  = t >> 6;
#pragma unroll
    for (int p = 0; p < 16; ++p) {
        int c = cq + p * 4;
        tile[c][nl] = f[((size_t)b * CC + c) * NN + n0 + nl];   // coalesced
    }
    __syncthreads();
#pragma unroll
    for (int p = 0; p < 16; ++p) {
        int nl2 = cq + p * 4;
        ft[((size_t)b * NN + n0 + nl2) * CC + nl] = tile[nl][nl2]; // coalesced
    }
}

// ---------------------------------------------------------------------------
// Kernel 2: fused ball-query + group. 256 threads = 4 waves, 4 queries/block
// (one per wave for the scan; block-cooperative grouping, sequential over the
// 4 queries through one 64x65 LDS tile). LDS ~17.7KB -> 8 blocks/CU ->
// 32 waves/CU. Scan does 2 points/lane/iter (128/iter) to halve iterations.
// ---------------------------------------------------------------------------
__global__ __launch_bounds__(256) void fused_qg(const float* __restrict__ xyz,
                                                const float* __restrict__ nxyz,
                                                const float* __restrict__ featT,
                                                float* __restrict__ out) {
    __shared__ float tile[64][65];
    __shared__ int   sidx[4][NSAMP];

    int t    = threadIdx.x;
    int wid  = t >> 6;
    int lane = t & 63;
    int wg   = blockIdx.x;
    // XCD swizzle: 4096 blocks, 512/XCD; each XCD's featT slice ~4MB = one L2.
    int qblk = (wg & 7) * (BB * SS / 8 / 4) + (wg >> 3);
    int q0   = qblk * 4;

    // ---- phase 1: ball query, one query per wave ----
    {
        int q = q0 + wid;
        int b = q >> 12;
        int s = q & (SS - 1);
        const float* xb = xyz + (size_t)b * NN * 3;
        float qx = nxyz[((size_t)b * SS + s) * 3 + 0];
        float qy = nxyz[((size_t)b * SS + s) * 3 + 1];
        float qz = nxyz[((size_t)b * SS + s) * 3 + 2];
        // q2 = (qx*qx + qy*qy) + qz*qz -- numpy f32 sequential, no FMA
        float q2 = __fadd_rn(__fadd_rn(__fmul_rn(qx, qx), __fmul_rn(qy, qy)),
                             __fmul_rn(qz, qz));

        int cnt = 0;
        // prefetch first 128 points (2 per lane)
        float px0 = xb[lane * 3 + 0], py0 = xb[lane * 3 + 1], pz0 = xb[lane * 3 + 2];
        float px1 = xb[(lane + 64) * 3 + 0], py1 = xb[(lane + 64) * 3 + 1],
              pz1 = xb[(lane + 64) * 3 + 2];
        for (int base = 0; base < NN; base += 128) {
            float ax = px0, ay = py0, az = pz0;
            float bx = px1, by = py1, bz = pz1;
            int nb = base + 128;
            if (nb < NN) {   // uniform; prefetch next 128
                px0 = xb[(nb + lane) * 3 + 0];
                py0 = xb[(nb + lane) * 3 + 1];
                pz0 = xb[(nb + lane) * 3 + 2];
                px1 = xb[(nb + 64 + lane) * 3 + 0];
                py1 = xb[(nb + 64 + lane) * 3 + 1];
                pz1 = xb[(nb + 64 + lane) * 3 + 2];
            }
            // d2 = (q2 + p2) - (qp + qp), all in numpy-sequential f32
            float p2a = __fadd_rn(__fadd_rn(__fmul_rn(ax, ax), __fmul_rn(ay, ay)),
                                  __fmul_rn(az, az));
            float qpa = __fadd_rn(__fadd_rn(__fmul_rn(qx, ax), __fmul_rn(qy, ay)),
                                  __fmul_rn(qz, az));
            float d2a = __fsub_rn(__fadd_rn(q2, p2a), __fadd_rn(qpa, qpa));
            float p2b = __fadd_rn(__fadd_rn(__fmul_rn(bx, bx), __fmul_rn(by, by)),
                                  __fmul_rn(bz, bz));
            float qpb = __fadd_rn(__fadd_rn(__fmul_rn(qx, bx), __fmul_rn(qy, by)),
                                  __fmul_rn(qz, bz));
            float d2b = __fsub_rn(__fadd_rn(q2, p2b), __fadd_rn(qpb, qpb));
            bool in0 = d2a < R2;
            bool in1 = d2b < R2;
            unsigned long long m0 = __ballot(in0);
            unsigned long long m1 = __ballot(in1);
            int c0 = __popcll(m0);
            if (in0) {
                int pos = cnt + __popcll(m0 & ((1ull << lane) - 1ull));
                if (pos < NSAMP) sidx[wid][pos] = base + lane;
            }
            if (in1) {
                int pos = cnt + c0 + __popcll(m1 & ((1ull << lane) - 1ull));
                if (pos < NSAMP) sidx[wid][pos] = base + 64 + lane;
            }
            cnt += c0 + __popcll(m1);
            if (cnt >= NSAMP) break;   // uniform
        }
        // wave-synchronous LDS access: drain ds ops, forbid reordering
        asm volatile("s_waitcnt lgkmcnt(0)" ::: "memory");
        int total = cnt < NSAMP ? cnt : NSAMP;
        int myidx = (total == 0) ? 0 : ((lane < total) ? sidx[wid][lane] : sidx[wid][0]);
        asm volatile("s_waitcnt lgkmcnt(0)" ::: "memory");
        sidx[wid][lane] = myidx;   // normalized (first-index-filled) list
    }
    __syncthreads();

    // ---- phase 2: grouping, 4 queries sequentially, whole block each ----
    int rsub = t >> 4;       // 0..15 (gather row sub-index)
    int cf4  = t & 15;       // 0..15 (float4 column)
    int k4   = t & 15;       // store: sample/4 index
#pragma unroll
    for (int qi = 0; qi < 4; ++qi) {
        int q = q0 + qi;
        int b = q >> 12;
        int s = q & (SS - 1);
        const float* ftb = featT + (size_t)b * NN * CC;
        // gather 64 rows x 64 ch into tile (coalesced 256B row reads)
#pragma unroll
        for (int j = 0; j < 4; ++j) {
            int row = j * 16 + rsub;
            int pr  = sidx[qi][row];
            const f32x4 v = *(const f32x4*)(ftb + (size_t)pr * CC + cf4 * 4);
            tile[row][cf4 * 4 + 0] = v.x;
            tile[row][cf4 * 4 + 1] = v.y;
            tile[row][cf4 * 4 + 2] = v.z;
            tile[row][cf4 * 4 + 3] = v.w;
        }
        size_t obase = ((size_t)b * 67) * SS * 64 + (size_t)s * 64;
        size_t chs   = (size_t)SS * 64;
        // xyz channels 0..2: handled by wave qi (rotates per query)
        if (wid == qi) {
            int id = sidx[qi][lane];
            float qx = nxyz[((size_t)b * SS + s) * 3 + 0];
            float qy = nxyz[((size_t)b * SS + s) * 3 + 1];
            float qz = nxyz[((size_t)b * SS + s) * 3 + 2];
            const float* xb = xyz + (size_t)b * NN * 3;
            float gx = __fsub_rn(xb[(size_t)id * 3 + 0], qx);
            float gy = __fsub_rn(xb[(size_t)id * 3 + 1], qy);
            float gz = __fsub_rn(xb[(size_t)id * 3 + 2], qz);
            __builtin_nontemporal_store(gx, out + obase + 0 * chs + lane);
            __builtin_nontemporal_store(gy, out + obase + 1 * chs + lane);
            __builtin_nontemporal_store(gz, out + obase + 2 * chs + lane);
        }
        __syncthreads();
        // feature channels 3..66: transposed tile reads, coalesced nt stores
#pragma unroll
        for (int j = 0; j < 4; ++j) {
            int c = j * 16 + (t >> 4);
            f32x4 o;
            o.x = tile[k4 * 4 + 0][c];
            o.y = tile[k4 * 4 + 1][c];
            o.z = tile[k4 * 4 + 2][c];
            o.w = tile[k4 * 4 + 3][c];
            __builtin_nontemporal_store(o,
                (f32x4*)(out + obase + (size_t)(3 + c) * chs + k4 * 4));
        }
        __syncthreads();   // protect tile before next query overwrites
    }
}

// ---------------------------------------------------------------------------
// Fallback (ws too small): fused one-wave-per-query, direct (C,N) gather.
// ---------------------------------------------------------------------------
__global__ __launch_bounds__(64) void qg_fallback(const float* __restrict__ xyz,
                                                  const float* __restrict__ nxyz,
                                                  const float* __restrict__ feat,
                                                  float* __restrict__ out) {
    __shared__ int sidx[NSAMP];
    int q = blockIdx.x;
    int b = q >> 12, s = q & (SS - 1);
    int lane = threadIdx.x;
    const float* xb = xyz + (size_t)b * NN * 3;
    float qx = nxyz[((size_t)b * SS + s) * 3 + 0];
    float qy = nxyz[((size_t)b * SS + s) * 3 + 1];
    float qz = nxyz[((size_t)b * SS + s) * 3 + 2];
    float q2 = __fadd_rn(__fadd_rn(__fmul_rn(qx, qx), __fmul_rn(qy, qy)),
                         __fmul_rn(qz, qz));
    int cnt = 0;
    for (int base = 0; base < NN; base += 64) {
        float cx = xb[(size_t)(base + lane) * 3 + 0];
        float cy = xb[(size_t)(base + lane) * 3 + 1];
        float cz = xb[(size_t)(base + lane) * 3 + 2];
        float p2 = __fadd_rn(__fadd_rn(__fmul_rn(cx, cx), __fmul_rn(cy, cy)),
                             __fmul_rn(cz, cz));
        float qp = __fadd_rn(__fadd_rn(__fmul_rn(qx, cx), __fmul_rn(qy, cy)),
                             __fmul_rn(qz, cz));
        float d2 = __fsub_rn(__fadd_rn(q2, p2), __fadd_rn(qp, qp));
        bool in = d2 < R2;
        unsigned long long m = __ballot(in);
        if (in) {
            int pos = cnt + __popcll(m & ((1ull << lane) - 1ull));
            if (pos < NSAMP) sidx[pos] = base + lane;
        }
        cnt += __popcll(m);
        if (cnt >= NSAMP) break;
    }
    __syncthreads();
    int total = cnt < NSAMP ? cnt : NSAMP;
    int myidx = (total == 0) ? 0 : ((lane < total) ? sidx[lane] : sidx[0]);
    size_t obase = ((size_t)b * 67) * SS * 64 + (size_t)s * 64;
    size_t chs   = (size_t)SS * 64;
    out[obase + 0 * chs + lane] = __fsub_rn(xb[(size_t)myidx * 3 + 0], qx);
    out[obase + 1 * chs + lane] = __fsub_rn(xb[(size_t)myidx * 3 + 1], qy);
    out[obase + 2 * chs + lane] = __fsub_rn(xb[(size_t)myidx * 3 + 2], qz);
    const float* fb = feat + (size_t)b * CC * NN;
#pragma unroll 4
    for (int c = 0; c < CC; ++c)
        out[obase + (size_t)(3 + c) * chs + lane] = fb[(size_t)c * NN + myidx];
}

// ---------------------------------------------------------------------------
extern "C" void kernel_launch(void* const* d_in, const int* in_sizes, int n_in,
                              void* d_out, int out_size, void* d_ws, size_t ws_size,
                              hipStream_t stream) {
    const float* xyz  = (const float*)d_in[0];   // (B,N,3)
    const float* nxyz = (const float*)d_in[1];   // (B,S,3)
    const float* feat = (const float*)d_in[2];   // (B,C,N)
    float* out = (float*)d_out;                  // (B,67,S,64)

    size_t needT = (size_t)BB * NN * CC * sizeof(float);   // 16 MB
    if (ws_size >= needT) {
        float* featT = (float*)d_ws;
        transpose_feat<<<BB * (NN / 64), 256, 0, stream>>>(feat, featT);
        fused_qg<<<BB * SS / 4, 256, 0, stream>>>(xyz, nxyz, featT, out);
    } else {
        qg_fallback<<<BB * SS, 64, 0, stream>>>(xyz, nxyz, feat, out);
    }
}